// Round 1
// baseline (1965.359 us; speedup 1.0000x reference)
//
#include <hip/hip_runtime.h>
#include <math.h>

// Dims: B=4 (b*n), L=1024 (h*w), D_MODEL=256, D_INNER=512, D_STATE=16, DT_RANK=16
// Streams: s=0 forward layer (2*it), s=1 backward layer (2*it+1), all stored natural time order.

__device__ __forceinline__ float sigmoidf_(float x){ return 1.f/(1.f+__expf(-x)); }

// hs[b,l,c] = x[b,c,l]
__global__ __launch_bounds__(256) void k_transpose_in(const float* __restrict__ x, float* __restrict__ hs){
  __shared__ float tile[32][33];
  int b = blockIdx.z;
  int l0 = blockIdx.x*32, c0 = blockIdx.y*32;
  int tx = threadIdx.x, ty = threadIdx.y;
  #pragma unroll
  for (int j=0;j<32;j+=8)
    tile[ty+j][tx] = x[(size_t)b*262144 + (size_t)(c0+ty+j)*1024 + l0 + tx];
  __syncthreads();
  #pragma unroll
  for (int j=0;j<32;j+=8)
    hs[(size_t)b*262144 + (size_t)(l0+ty+j)*256 + (c0+tx)] = tile[tx][ty+j];
}

// out[b,c,l] = 2*racc[b,l,c] + hs[b,l,c]
__global__ __launch_bounds__(256) void k_final(const float* __restrict__ racc, const float* __restrict__ hs, float* __restrict__ out){
  __shared__ float tile[32][33];
  int b = blockIdx.z;
  int l0 = blockIdx.x*32, c0 = blockIdx.y*32;
  int tx = threadIdx.x, ty = threadIdx.y;
  #pragma unroll
  for (int j=0;j<32;j+=8){
    size_t idx = (size_t)b*262144 + (size_t)(l0+ty+j)*256 + c0+tx;
    tile[ty+j][tx] = 2.f*racc[idx] + hs[idx];
  }
  __syncthreads();
  #pragma unroll
  for (int j=0;j<32;j+=8)
    out[(size_t)b*262144 + (size_t)(c0+ty+j)*1024 + l0+tx] = tile[tx][ty+j];
}

// r = hs (+ 2*racc on iter1); racc = r; hn[s] = LN(r)*nw[layer0+s] + nb[layer0+s] for s=0,1
__global__ __launch_bounds__(256) void k_ln(const float* __restrict__ hs, float* __restrict__ racc, float* __restrict__ hn,
  const float* __restrict__ nw, const float* __restrict__ nb, int layer0, int first){
  int row = blockIdx.x, c = threadIdx.x;
  size_t idx = (size_t)row*256 + c;
  float r = hs[idx];
  if (!first) r += 2.f*racc[idx];
  racc[idx] = r;
  float s1=r, s2=r*r;
  #pragma unroll
  for (int o=32;o>=1;o>>=1){ s1+=__shfl_xor(s1,o); s2+=__shfl_xor(s2,o); }
  __shared__ float red[8];
  int wid=c>>6, lane=c&63;
  if (lane==0){ red[wid]=s1; red[4+wid]=s2; }
  __syncthreads();
  s1 = red[0]+red[1]+red[2]+red[3];
  s2 = red[4]+red[5]+red[6]+red[7];
  float mu = s1*(1.f/256.f);
  float var = s2*(1.f/256.f) - mu*mu;
  float inv = rsqrtf(var + 1e-5f);
  float nv = (r-mu)*inv;
  hn[idx] = nv*nw[layer0*256+c] + nb[layer0*256+c];
  hn[(size_t)1048576 + idx] = nv*nw[(layer0+1)*256+c] + nb[(layer0+1)*256+c];
}

// C[M,N] = act(A[M,K] @ W[N,K]^T + bias), optional accumulate. 64x64 tile, 4x4/thread.
__global__ __launch_bounds__(256) void k_gemm(
  const float* __restrict__ Ab, long sA,
  const float* __restrict__ Wb, long sW,
  float* __restrict__ Cb, long sC,
  const float* __restrict__ biasb, long sBias,
  int M, int N, int K, int lda, int ldw, int ldc, int act, int accum)
{
  int z = blockIdx.z;
  const float* A = Ab + (size_t)z*sA;
  const float* W = Wb + (size_t)z*sW;
  float* C = Cb + (size_t)z*sC;
  __shared__ float As[16][64];
  __shared__ float Ws[16][64];
  int tid = threadIdx.x;
  int tx = tid & 15, ty = tid >> 4;
  int row0 = blockIdx.y*64, col0 = blockIdx.x*64;
  int lr = tid >> 2, lk = (tid & 3)*4;
  float acc[4][4] = {};
  for (int k0=0;k0<K;k0+=16){
    float4 av = *(const float4*)(A + (size_t)(row0+lr)*lda + k0 + lk);
    float4 wv = make_float4(0.f,0.f,0.f,0.f);
    if (col0 + lr < N) wv = *(const float4*)(W + (size_t)(col0+lr)*ldw + k0 + lk);
    __syncthreads();
    As[lk+0][lr]=av.x; As[lk+1][lr]=av.y; As[lk+2][lr]=av.z; As[lk+3][lr]=av.w;
    Ws[lk+0][lr]=wv.x; Ws[lk+1][lr]=wv.y; Ws[lk+2][lr]=wv.z; Ws[lk+3][lr]=wv.w;
    __syncthreads();
    #pragma unroll
    for (int k=0;k<16;++k){
      float4 a = *(const float4*)&As[k][ty*4];
      float4 bv = *(const float4*)&Ws[k][tx*4];
      float ar[4] = {a.x,a.y,a.z,a.w};
      float br[4] = {bv.x,bv.y,bv.z,bv.w};
      #pragma unroll
      for (int r=0;r<4;++r)
        #pragma unroll
        for (int cc=0;cc<4;++cc)
          acc[r][cc] = fmaf(ar[r], br[cc], acc[r][cc]);
    }
  }
  const float* bias = biasb ? biasb + (size_t)z*sBias : nullptr;
  #pragma unroll
  for (int r=0;r<4;++r){
    int row = row0 + ty*4 + r;
    #pragma unroll
    for (int cc=0;cc<4;++cc){
      int col = col0 + tx*4 + cc;
      if (col < N){
        float v = acc[r][cc];
        if (bias) v += bias[col];
        if (act==1){ v = (v > 20.f) ? v : log1pf(__expf(v)); }
        size_t oi = (size_t)row*ldc + col;
        if (accum) C[oi] += v; else C[oi] = v;
      }
    }
  }
}

// causal (s=0) / anticausal (s=1) depthwise conv over t + SiLU. x = first half of xz rows.
__global__ __launch_bounds__(256) void k_conv(const float* __restrict__ xz, float* __restrict__ xc,
  const float* __restrict__ cw, const float* __restrict__ cb, int layer0){
  int idx = blockIdx.x*256 + threadIdx.x;   // (sb, t, d), d fastest
  int d = idx & 511;
  int t = (idx >> 9) & 1023;
  int sb = idx >> 19;                        // s*4 + b
  int s = sb >> 2;
  int layer = layer0 + s;
  const float* w = cw + ((size_t)layer*512 + d)*4;
  float accv = cb[(size_t)layer*512 + d];
  const float* xp = xz + (size_t)sb*1048576;  // row stride 1024, x part at [0:512)
  if (s==0){
    #pragma unroll
    for (int k=0;k<4;++k){ int tt = t + k - 3; if (tt>=0) accv = fmaf(xp[(size_t)tt*1024 + d], w[k], accv); }
  } else {
    #pragma unroll
    for (int k=0;k<4;++k){ int tt = t + 3 - k; if (tt<1024) accv = fmaf(xp[(size_t)tt*1024 + d], w[k], accv); }
  }
  xc[idx] = accv * sigmoidf_(accv);
}

// selective scan; thread = (d,n) pair; 16-lane shuffle reduce; y (gated) overwrites dtv.
__global__ __launch_bounds__(256) void k_scan(
  float* __restrict__ dtv, const float* __restrict__ xc, const float* __restrict__ xz,
  const float* __restrict__ dbl, const float* __restrict__ A_log, const float* __restrict__ Dp,
  int layer0)
{
  int tid = threadIdx.x;
  int n = tid & 15, dl = tid >> 4;
  int d = blockIdx.x*16 + dl;
  int b = blockIdx.y, s = blockIdx.z;
  int layer = layer0 + s;
  float Av = -__expf(A_log[((size_t)layer*512 + d)*16 + n]);
  float Dv = Dp[(size_t)layer*512 + d];
  size_t sb = (size_t)s*4 + b;
  float* dt_p = dtv + sb*524288 + d;          // stride 512 per t
  const float* xc_p = xc + sb*524288 + d;
  const float* z_p = xz + sb*1048576 + 512 + d; // stride 1024 per t
  const float* bc_p = dbl + sb*49152;          // stride 48 per t
  float h = 0.f;
  int t = (s==0) ? 0 : 1023;
  int st = (s==0) ? 1 : -1;
  for (int step=0; step<1024; ++step, t += st){
    float dtval = dt_p[(size_t)t*512];
    float xv = xc_p[(size_t)t*512];
    float Bv = bc_p[t*48 + 16 + n];
    float Cv = bc_p[t*48 + 32 + n];
    h = __expf(dtval*Av)*h + dtval*Bv*xv;
    float p = h*Cv;
    p += __shfl_xor(p,1); p += __shfl_xor(p,2);
    p += __shfl_xor(p,4); p += __shfl_xor(p,8);
    if (n==0){
      float zv = z_p[(size_t)t*1024];
      dt_p[(size_t)t*512] = (p + Dv*xv) * (zv*sigmoidf_(zv));
    }
  }
}

extern "C" void kernel_launch(void* const* d_in, const int* in_sizes, int n_in,
                              void* d_out, int out_size, void* d_ws, size_t ws_size,
                              hipStream_t stream) {
  const float* x        = (const float*)d_in[0];
  const float* norm_w   = (const float*)d_in[1];
  const float* norm_b   = (const float*)d_in[2];
  const float* in_w     = (const float*)d_in[3];
  const float* conv_w   = (const float*)d_in[4];
  const float* conv_b   = (const float*)d_in[5];
  const float* xproj_w  = (const float*)d_in[6];
  const float* dtproj_w = (const float*)d_in[7];
  const float* dtproj_b = (const float*)d_in[8];
  const float* A_log    = (const float*)d_in[9];
  const float* Dp       = (const float*)d_in[10];
  const float* out_w    = (const float*)d_in[11];
  float* out = (float*)d_out;
  float* ws = (float*)d_ws;

  float* hs   = ws;              // 1048576
  float* racc = ws + 1048576;    // 1048576
  float* hn   = ws + 2097152;    // 2*1048576 (2 streams)
  float* xz   = ws + 4194304;    // 2*4*1024*1024 = 8388608
  float* xc   = ws + 12582912;   // 2*4*1024*512  = 4194304
  float* dbl  = ws + 16777216;   // 2*4*1024*48   = 393216
  float* dtv  = ws + 17170432;   // 4194304 (dt in, gated y out)

  k_transpose_in<<<dim3(32,8,4), dim3(32,8), 0, stream>>>(x, hs);

  for (int it=0; it<2; ++it){
    int layer0 = 2*it;
    k_ln<<<4096, 256, 0, stream>>>(hs, racc, hn, norm_w, norm_b, layer0, it==0 ? 1 : 0);
    // in_proj: xz[s] = hn[s] @ in_w[layer0+s]^T   (M=4096, N=1024, K=256)
    k_gemm<<<dim3(16,64,2), 256, 0, stream>>>(hn, 1048576L, in_w + (size_t)layer0*262144, 262144L,
        xz, 4194304L, nullptr, 0L, 4096, 1024, 256, 256, 256, 1024, 0, 0);
    k_conv<<<16384, 256, 0, stream>>>(xz, xc, conv_w, conv_b, layer0);
    // xproj: dbl[s] = xc[s] @ xproj_w[layer0+s]^T  (M=4096, N=48, K=512)
    k_gemm<<<dim3(1,64,2), 256, 0, stream>>>(xc, 2097152L, xproj_w + (size_t)layer0*24576, 24576L,
        dbl, 196608L, nullptr, 0L, 4096, 48, 512, 512, 512, 48, 0, 0);
    // dtproj: dtv[s] = softplus(dbl[s][:, :16] @ dtproj_w^T + b)  (M=4096, N=512, K=16)
    k_gemm<<<dim3(8,64,2), 256, 0, stream>>>(dbl, 196608L, dtproj_w + (size_t)layer0*8192, 8192L,
        dtv, 2097152L, dtproj_b + (size_t)layer0*512, 512L, 4096, 512, 16, 48, 16, 512, 1, 0);
    k_scan<<<dim3(32,4,2), 256, 0, stream>>>(dtv, xc, xz, dbl, A_log, Dp, layer0);
    // out_proj: hs = y_f @ out_w[layer0]^T + y_b @ out_w[layer0+1]^T
    k_gemm<<<dim3(4,64,1), 256, 0, stream>>>(dtv, 0L, out_w + (size_t)layer0*131072, 0L,
        hs, 0L, nullptr, 0L, 4096, 256, 512, 512, 512, 256, 0, 0);
    k_gemm<<<dim3(4,64,1), 256, 0, stream>>>(dtv + 2097152, 0L, out_w + (size_t)(layer0+1)*131072, 0L,
        hs, 0L, nullptr, 0L, 4096, 256, 512, 512, 512, 256, 0, 1);
  }
  k_final<<<dim3(32,8,4), dim3(32,8), 0, stream>>>(racc, hs, out);
}

// Round 2
// 781.751 us; speedup vs baseline: 2.5140x; 2.5140x over previous
//
#include <hip/hip_runtime.h>
#include <math.h>

// Dims: B=4 (b*n), L=1024 (h*w), D_MODEL=256, D_INNER=512, D_STATE=16, DT_RANK=16
// Streams: s=0 forward layer (2*it), s=1 backward layer (2*it+1), all stored natural time order.
// Scan: chunked 2-pass linear-recurrence scan, 16 chunks x 64 steps.

__device__ __forceinline__ float sigmoidf_(float x){ return 1.f/(1.f+__expf(-x)); }

// hs[b,l,c] = x[b,c,l]
__global__ __launch_bounds__(256) void k_transpose_in(const float* __restrict__ x, float* __restrict__ hs){
  __shared__ float tile[32][33];
  int b = blockIdx.z;
  int l0 = blockIdx.x*32, c0 = blockIdx.y*32;
  int tx = threadIdx.x, ty = threadIdx.y;
  #pragma unroll
  for (int j=0;j<32;j+=8)
    tile[ty+j][tx] = x[(size_t)b*262144 + (size_t)(c0+ty+j)*1024 + l0 + tx];
  __syncthreads();
  #pragma unroll
  for (int j=0;j<32;j+=8)
    hs[(size_t)b*262144 + (size_t)(l0+ty+j)*256 + (c0+tx)] = tile[tx][ty+j];
}

// out[b,c,l] = 2*racc[b,l,c] + hs[b,l,c]
__global__ __launch_bounds__(256) void k_final(const float* __restrict__ racc, const float* __restrict__ hs, float* __restrict__ out){
  __shared__ float tile[32][33];
  int b = blockIdx.z;
  int l0 = blockIdx.x*32, c0 = blockIdx.y*32;
  int tx = threadIdx.x, ty = threadIdx.y;
  #pragma unroll
  for (int j=0;j<32;j+=8){
    size_t idx = (size_t)b*262144 + (size_t)(l0+ty+j)*256 + c0+tx;
    tile[ty+j][tx] = 2.f*racc[idx] + hs[idx];
  }
  __syncthreads();
  #pragma unroll
  for (int j=0;j<32;j+=8)
    out[(size_t)b*262144 + (size_t)(c0+ty+j)*1024 + l0+tx] = tile[tx][ty+j];
}

// r = hs (+ 2*racc on iter1); racc = r; hn[s] = LN(r)*nw[layer0+s] + nb[layer0+s] for s=0,1
__global__ __launch_bounds__(256) void k_ln(const float* __restrict__ hs, float* __restrict__ racc, float* __restrict__ hn,
  const float* __restrict__ nw, const float* __restrict__ nb, int layer0, int first){
  int row = blockIdx.x, c = threadIdx.x;
  size_t idx = (size_t)row*256 + c;
  float r = hs[idx];
  if (!first) r += 2.f*racc[idx];
  racc[idx] = r;
  float s1=r, s2=r*r;
  #pragma unroll
  for (int o=32;o>=1;o>>=1){ s1+=__shfl_xor(s1,o); s2+=__shfl_xor(s2,o); }
  __shared__ float red[8];
  int wid=c>>6, lane=c&63;
  if (lane==0){ red[wid]=s1; red[4+wid]=s2; }
  __syncthreads();
  s1 = red[0]+red[1]+red[2]+red[3];
  s2 = red[4]+red[5]+red[6]+red[7];
  float mu = s1*(1.f/256.f);
  float var = s2*(1.f/256.f) - mu*mu;
  float inv = rsqrtf(var + 1e-5f);
  float nv = (r-mu)*inv;
  hn[idx] = nv*nw[layer0*256+c] + nb[layer0*256+c];
  hn[(size_t)1048576 + idx] = nv*nw[(layer0+1)*256+c] + nb[(layer0+1)*256+c];
}

// C[M,N] = act(A[M,K] @ W[N,K]^T + bias), optional accumulate. 64x64 tile, 4x4/thread.
__global__ __launch_bounds__(256) void k_gemm(
  const float* __restrict__ Ab, long sA,
  const float* __restrict__ Wb, long sW,
  float* __restrict__ Cb, long sC,
  const float* __restrict__ biasb, long sBias,
  int M, int N, int K, int lda, int ldw, int ldc, int act, int accum)
{
  int z = blockIdx.z;
  const float* A = Ab + (size_t)z*sA;
  const float* W = Wb + (size_t)z*sW;
  float* C = Cb + (size_t)z*sC;
  __shared__ float As[16][64];
  __shared__ float Ws[16][64];
  int tid = threadIdx.x;
  int tx = tid & 15, ty = tid >> 4;
  int row0 = blockIdx.y*64, col0 = blockIdx.x*64;
  int lr = tid >> 2, lk = (tid & 3)*4;
  float acc[4][4] = {};
  for (int k0=0;k0<K;k0+=16){
    float4 av = *(const float4*)(A + (size_t)(row0+lr)*lda + k0 + lk);
    float4 wv = make_float4(0.f,0.f,0.f,0.f);
    if (col0 + lr < N) wv = *(const float4*)(W + (size_t)(col0+lr)*ldw + k0 + lk);
    __syncthreads();
    As[lk+0][lr]=av.x; As[lk+1][lr]=av.y; As[lk+2][lr]=av.z; As[lk+3][lr]=av.w;
    Ws[lk+0][lr]=wv.x; Ws[lk+1][lr]=wv.y; Ws[lk+2][lr]=wv.z; Ws[lk+3][lr]=wv.w;
    __syncthreads();
    #pragma unroll
    for (int k=0;k<16;++k){
      float4 a = *(const float4*)&As[k][ty*4];
      float4 bv = *(const float4*)&Ws[k][tx*4];
      float ar[4] = {a.x,a.y,a.z,a.w};
      float br[4] = {bv.x,bv.y,bv.z,bv.w};
      #pragma unroll
      for (int r=0;r<4;++r)
        #pragma unroll
        for (int cc=0;cc<4;++cc)
          acc[r][cc] = fmaf(ar[r], br[cc], acc[r][cc]);
    }
  }
  const float* bias = biasb ? biasb + (size_t)z*sBias : nullptr;
  #pragma unroll
  for (int r=0;r<4;++r){
    int row = row0 + ty*4 + r;
    #pragma unroll
    for (int cc=0;cc<4;++cc){
      int col = col0 + tx*4 + cc;
      if (col < N){
        float v = acc[r][cc];
        if (bias) v += bias[col];
        if (act==1){ v = (v > 20.f) ? v : log1pf(__expf(v)); }
        size_t oi = (size_t)row*ldc + col;
        if (accum) C[oi] += v; else C[oi] = v;
      }
    }
  }
}

// causal (s=0) / anticausal (s=1) depthwise conv over t + SiLU. x = first half of xz rows.
__global__ __launch_bounds__(256) void k_conv(const float* __restrict__ xz, float* __restrict__ xc,
  const float* __restrict__ cw, const float* __restrict__ cb, int layer0){
  int idx = blockIdx.x*256 + threadIdx.x;   // (sb, t, d), d fastest
  int d = idx & 511;
  int t = (idx >> 9) & 1023;
  int sb = idx >> 19;                        // s*4 + b
  int s = sb >> 2;
  int layer = layer0 + s;
  const float* w = cw + ((size_t)layer*512 + d)*4;
  float accv = cb[(size_t)layer*512 + d];
  const float* xp = xz + (size_t)sb*1048576;  // row stride 1024, x part at [0:512)
  if (s==0){
    #pragma unroll
    for (int k=0;k<4;++k){ int tt = t + k - 3; if (tt>=0) accv = fmaf(xp[(size_t)tt*1024 + d], w[k], accv); }
  } else {
    #pragma unroll
    for (int k=0;k<4;++k){ int tt = t + 3 - k; if (tt<1024) accv = fmaf(xp[(size_t)tt*1024 + d], w[k], accv); }
  }
  xc[idx] = accv * sigmoidf_(accv);
}

// ---- chunked scan: 16 chunks x 64 steps, processing order u=0..1023, t = s ? 1023-u : u ----

// Pass A: per-chunk (prod a, h from h0=0). block=(dtile,chunk,sb), thread=(n,dl).
__global__ __launch_bounds__(256) void k_scan_a(
  const float* __restrict__ dtv, const float* __restrict__ xc,
  const float* __restrict__ dbl, const float* __restrict__ A_log,
  float* __restrict__ aP, float* __restrict__ hF, int layer0)
{
  int tid = threadIdx.x;
  int n = tid & 15, dl = tid >> 4;
  int d = blockIdx.x*16 + dl;
  int k = blockIdx.y;
  int sb = blockIdx.z;
  int s = sb >> 2;
  int layer = layer0 + s;
  float Av = -__expf(A_log[((size_t)layer*512 + d)*16 + n]);
  const float* dt_p = dtv + (size_t)sb*524288 + d;
  const float* xc_p = xc + (size_t)sb*524288 + d;
  const float* bc_p = dbl + (size_t)sb*49152;
  float h = 0.f, ap = 1.f;
  int u0 = k*64;
  for (int i=0;i<64;++i){
    int u = u0 + i;
    int t = s ? (1023 - u) : u;
    float dtval = dt_p[(size_t)t*512];
    float xv = xc_p[(size_t)t*512];
    float Bv = bc_p[t*48 + 16 + n];
    float a = __expf(dtval*Av);
    h = a*h + dtval*Bv*xv;
    ap *= a;
  }
  size_t oi = ((size_t)(sb*16 + k)*512 + d)*16 + n;
  aP[oi] = ap;
  hF[oi] = h;
}

// Combine: serial over 16 chunks per (sb,d,n); h0 overwrites aP in place.
__global__ __launch_bounds__(256) void k_scan_c(float* __restrict__ aP, const float* __restrict__ hF){
  int gid = blockIdx.x*256 + threadIdx.x;  // sb*8192 + d*16 + n
  int sb = gid >> 13;
  int rem = gid & 8191;
  float hrun = 0.f;
  #pragma unroll
  for (int k=0;k<16;++k){
    size_t idx = (size_t)(sb*16 + k)*8192 + rem;
    float a = aP[idx];
    float hf = hF[idx];
    aP[idx] = hrun;          // h0 for chunk k
    hrun = a*hrun + hf;
  }
}

// Pass B: recompute within chunk from h0, emit gated y in place of dt (same element, read-before-write).
__global__ __launch_bounds__(256) void k_scan_b(
  float* __restrict__ dty, const float* __restrict__ xc, const float* __restrict__ xz,
  const float* __restrict__ dbl, const float* __restrict__ A_log, const float* __restrict__ Dp,
  const float* __restrict__ h0, int layer0)
{
  int tid = threadIdx.x;
  int n = tid & 15, dl = tid >> 4;
  int d = blockIdx.x*16 + dl;
  int k = blockIdx.y;
  int sb = blockIdx.z;
  int s = sb >> 2;
  int layer = layer0 + s;
  float Av = -__expf(A_log[((size_t)layer*512 + d)*16 + n]);
  float Dv = Dp[(size_t)layer*512 + d];
  float* dt_p = dty + (size_t)sb*524288 + d;
  const float* xc_p = xc + (size_t)sb*524288 + d;
  const float* z_p = xz + (size_t)sb*1048576 + 512 + d;
  const float* bc_p = dbl + (size_t)sb*49152;
  float h = h0[((size_t)(sb*16 + k)*512 + d)*16 + n];
  int u0 = k*64;
  for (int i=0;i<64;++i){
    int u = u0 + i;
    int t = s ? (1023 - u) : u;
    float dtval = dt_p[(size_t)t*512];
    float xv = xc_p[(size_t)t*512];
    float Bv = bc_p[t*48 + 16 + n];
    float Cv = bc_p[t*48 + 32 + n];
    float a = __expf(dtval*Av);
    h = a*h + dtval*Bv*xv;
    float p = h*Cv;
    p += __shfl_xor(p,1); p += __shfl_xor(p,2);
    p += __shfl_xor(p,4); p += __shfl_xor(p,8);
    if (n==0){
      float zv = z_p[(size_t)t*1024];
      dt_p[(size_t)t*512] = (p + Dv*xv) * (zv*sigmoidf_(zv));
    }
  }
}

extern "C" void kernel_launch(void* const* d_in, const int* in_sizes, int n_in,
                              void* d_out, int out_size, void* d_ws, size_t ws_size,
                              hipStream_t stream) {
  const float* x        = (const float*)d_in[0];
  const float* norm_w   = (const float*)d_in[1];
  const float* norm_b   = (const float*)d_in[2];
  const float* in_w     = (const float*)d_in[3];
  const float* conv_w   = (const float*)d_in[4];
  const float* conv_b   = (const float*)d_in[5];
  const float* xproj_w  = (const float*)d_in[6];
  const float* dtproj_w = (const float*)d_in[7];
  const float* dtproj_b = (const float*)d_in[8];
  const float* A_log    = (const float*)d_in[9];
  const float* Dp       = (const float*)d_in[10];
  const float* out_w    = (const float*)d_in[11];
  float* out = (float*)d_out;
  float* ws = (float*)d_ws;

  float* hs   = ws;              // 1048576
  float* racc = ws + 1048576;    // 1048576
  float* hn   = ws + 2097152;    // 2*1048576 (2 streams); dead after in_proj -> reused for aP/hF
  float* xz   = ws + 4194304;    // 8388608
  float* xc   = ws + 12582912;   // 4194304
  float* dbl  = ws + 16777216;   // 393216
  float* dtv  = ws + 17170432;   // 4194304 (dt in, gated y out in-place)
  float* aP   = hn;              // 1048576 (8 sb x 16 chunk x 512 d x 16 n)
  float* hF   = hn + 1048576;    // 1048576

  k_transpose_in<<<dim3(32,8,4), dim3(32,8), 0, stream>>>(x, hs);

  for (int it=0; it<2; ++it){
    int layer0 = 2*it;
    k_ln<<<4096, 256, 0, stream>>>(hs, racc, hn, norm_w, norm_b, layer0, it==0 ? 1 : 0);
    // in_proj: xz[s] = hn[s] @ in_w[layer0+s]^T   (M=4096, N=1024, K=256)
    k_gemm<<<dim3(16,64,2), 256, 0, stream>>>(hn, 1048576L, in_w + (size_t)layer0*262144, 262144L,
        xz, 4194304L, nullptr, 0L, 4096, 1024, 256, 256, 256, 1024, 0, 0);
    k_conv<<<16384, 256, 0, stream>>>(xz, xc, conv_w, conv_b, layer0);
    // xproj: dbl[s] = xc[s] @ xproj_w[layer0+s]^T  (M=4096, N=48, K=512)
    k_gemm<<<dim3(1,64,2), 256, 0, stream>>>(xc, 2097152L, xproj_w + (size_t)layer0*24576, 24576L,
        dbl, 196608L, nullptr, 0L, 4096, 48, 512, 512, 512, 48, 0, 0);
    // dtproj: dtv[s] = softplus(dbl[s][:, :16] @ dtproj_w^T + b)  (M=4096, N=512, K=16)
    k_gemm<<<dim3(8,64,2), 256, 0, stream>>>(dbl, 196608L, dtproj_w + (size_t)layer0*8192, 8192L,
        dtv, 2097152L, dtproj_b + (size_t)layer0*512, 512L, 4096, 512, 16, 48, 16, 512, 1, 0);
    // chunked scan
    k_scan_a<<<dim3(32,16,8), 256, 0, stream>>>(dtv, xc, dbl, A_log, aP, hF, layer0);
    k_scan_c<<<256, 256, 0, stream>>>(aP, hF);
    k_scan_b<<<dim3(32,16,8), 256, 0, stream>>>(dtv, xc, xz, dbl, A_log, Dp, aP, layer0);
    // out_proj: hs = y_f @ out_w[layer0]^T + y_b @ out_w[layer0+1]^T
    k_gemm<<<dim3(4,64,1), 256, 0, stream>>>(dtv, 0L, out_w + (size_t)layer0*131072, 0L,
        hs, 0L, nullptr, 0L, 4096, 256, 512, 512, 512, 256, 0, 0);
    k_gemm<<<dim3(4,64,1), 256, 0, stream>>>(dtv + 2097152, 0L, out_w + (size_t)(layer0+1)*131072, 0L,
        hs, 0L, nullptr, 0L, 4096, 256, 512, 512, 512, 256, 0, 1);
  }
  k_final<<<dim3(32,8,4), dim3(32,8), 0, stream>>>(racc, hs, out);
}

// Round 3
// 593.447 us; speedup vs baseline: 3.3118x; 1.3173x over previous
//
#include <hip/hip_runtime.h>
#include <math.h>

// Dims: B=4 (b*n), L=1024 (h*w), D_MODEL=256, D_INNER=512, D_STATE=16, DT_RANK=16
// Streams: s=0 forward layer (2*it), s=1 backward layer (2*it+1), natural time order.
// Scan: chunked 2-pass, 32 chunks x 32 steps, thread-per-d with 16 states in registers.

__device__ __forceinline__ float sigmoidf_(float x){ return 1.f/(1.f+__expf(-x)); }

// hs[b,l,c] = x[b,c,l]
__global__ __launch_bounds__(256) void k_transpose_in(const float* __restrict__ x, float* __restrict__ hs){
  __shared__ float tile[32][33];
  int b = blockIdx.z;
  int l0 = blockIdx.x*32, c0 = blockIdx.y*32;
  int tx = threadIdx.x, ty = threadIdx.y;
  #pragma unroll
  for (int j=0;j<32;j+=8)
    tile[ty+j][tx] = x[(size_t)b*262144 + (size_t)(c0+ty+j)*1024 + l0 + tx];
  __syncthreads();
  #pragma unroll
  for (int j=0;j<32;j+=8)
    hs[(size_t)b*262144 + (size_t)(l0+ty+j)*256 + (c0+tx)] = tile[tx][ty+j];
}

// out[b,c,l] = 2*racc[b,l,c] + hs[b,l,c]
__global__ __launch_bounds__(256) void k_final(const float* __restrict__ racc, const float* __restrict__ hs, float* __restrict__ out){
  __shared__ float tile[32][33];
  int b = blockIdx.z;
  int l0 = blockIdx.x*32, c0 = blockIdx.y*32;
  int tx = threadIdx.x, ty = threadIdx.y;
  #pragma unroll
  for (int j=0;j<32;j+=8){
    size_t idx = (size_t)b*262144 + (size_t)(l0+ty+j)*256 + c0+tx;
    tile[ty+j][tx] = 2.f*racc[idx] + hs[idx];
  }
  __syncthreads();
  #pragma unroll
  for (int j=0;j<32;j+=8)
    out[(size_t)b*262144 + (size_t)(c0+ty+j)*1024 + l0+tx] = tile[tx][ty+j];
}

// r = hs (+ 2*racc on iter1); racc = r; hn[s] = LN(r)*nw[layer0+s] + nb[layer0+s] for s=0,1
__global__ __launch_bounds__(256) void k_ln(const float* __restrict__ hs, float* __restrict__ racc, float* __restrict__ hn,
  const float* __restrict__ nw, const float* __restrict__ nb, int layer0, int first){
  int row = blockIdx.x, c = threadIdx.x;
  size_t idx = (size_t)row*256 + c;
  float r = hs[idx];
  if (!first) r += 2.f*racc[idx];
  racc[idx] = r;
  float s1=r, s2=r*r;
  #pragma unroll
  for (int o=32;o>=1;o>>=1){ s1+=__shfl_xor(s1,o); s2+=__shfl_xor(s2,o); }
  __shared__ float red[8];
  int wid=c>>6, lane=c&63;
  if (lane==0){ red[wid]=s1; red[4+wid]=s2; }
  __syncthreads();
  s1 = red[0]+red[1]+red[2]+red[3];
  s2 = red[4]+red[5]+red[6]+red[7];
  float mu = s1*(1.f/256.f);
  float var = s2*(1.f/256.f) - mu*mu;
  float inv = rsqrtf(var + 1e-5f);
  float nv = (r-mu)*inv;
  hn[idx] = nv*nw[layer0*256+c] + nb[layer0*256+c];
  hn[(size_t)1048576 + idx] = nv*nw[(layer0+1)*256+c] + nb[(layer0+1)*256+c];
}

// C[M,N] = act(A[M,K] @ W[N,K]^T + bias), optional accumulate. 64x64 tile, 4x4/thread.
__global__ __launch_bounds__(256) void k_gemm(
  const float* __restrict__ Ab, long sA,
  const float* __restrict__ Wb, long sW,
  float* __restrict__ Cb, long sC,
  const float* __restrict__ biasb, long sBias,
  int M, int N, int K, int lda, int ldw, int ldc, int act, int accum)
{
  int z = blockIdx.z;
  const float* A = Ab + (size_t)z*sA;
  const float* W = Wb + (size_t)z*sW;
  float* C = Cb + (size_t)z*sC;
  __shared__ float As[16][64];
  __shared__ float Ws[16][64];
  int tid = threadIdx.x;
  int tx = tid & 15, ty = tid >> 4;
  int row0 = blockIdx.y*64, col0 = blockIdx.x*64;
  int lr = tid >> 2, lk = (tid & 3)*4;
  float acc[4][4] = {};
  for (int k0=0;k0<K;k0+=16){
    float4 av = *(const float4*)(A + (size_t)(row0+lr)*lda + k0 + lk);
    float4 wv = make_float4(0.f,0.f,0.f,0.f);
    if (col0 + lr < N) wv = *(const float4*)(W + (size_t)(col0+lr)*ldw + k0 + lk);
    __syncthreads();
    As[lk+0][lr]=av.x; As[lk+1][lr]=av.y; As[lk+2][lr]=av.z; As[lk+3][lr]=av.w;
    Ws[lk+0][lr]=wv.x; Ws[lk+1][lr]=wv.y; Ws[lk+2][lr]=wv.z; Ws[lk+3][lr]=wv.w;
    __syncthreads();
    #pragma unroll
    for (int k=0;k<16;++k){
      float4 a = *(const float4*)&As[k][ty*4];
      float4 bv = *(const float4*)&Ws[k][tx*4];
      float ar[4] = {a.x,a.y,a.z,a.w};
      float br[4] = {bv.x,bv.y,bv.z,bv.w};
      #pragma unroll
      for (int r=0;r<4;++r)
        #pragma unroll
        for (int cc=0;cc<4;++cc)
          acc[r][cc] = fmaf(ar[r], br[cc], acc[r][cc]);
    }
  }
  const float* bias = biasb ? biasb + (size_t)z*sBias : nullptr;
  #pragma unroll
  for (int r=0;r<4;++r){
    int row = row0 + ty*4 + r;
    #pragma unroll
    for (int cc=0;cc<4;++cc){
      int col = col0 + tx*4 + cc;
      if (col < N){
        float v = acc[r][cc];
        if (bias) v += bias[col];
        if (act==1){ v = (v > 20.f) ? v : log1pf(__expf(v)); }
        size_t oi = (size_t)row*ldc + col;
        if (accum) C[oi] += v; else C[oi] = v;
      }
    }
  }
}

// causal (s=0) / anticausal (s=1) depthwise conv over t + SiLU. x = first half of xz rows.
__global__ __launch_bounds__(256) void k_conv(const float* __restrict__ xz, float* __restrict__ xc,
  const float* __restrict__ cw, const float* __restrict__ cb, int layer0){
  int idx = blockIdx.x*256 + threadIdx.x;   // (sb, t, d), d fastest
  int d = idx & 511;
  int t = (idx >> 9) & 1023;
  int sb = idx >> 19;                        // s*4 + b
  int s = sb >> 2;
  int layer = layer0 + s;
  const float* w = cw + ((size_t)layer*512 + d)*4;
  float accv = cb[(size_t)layer*512 + d];
  const float* xp = xz + (size_t)sb*1048576;  // row stride 1024, x part at [0:512)
  if (s==0){
    #pragma unroll
    for (int k=0;k<4;++k){ int tt = t + k - 3; if (tt>=0) accv = fmaf(xp[(size_t)tt*1024 + d], w[k], accv); }
  } else {
    #pragma unroll
    for (int k=0;k<4;++k){ int tt = t + 3 - k; if (tt<1024) accv = fmaf(xp[(size_t)tt*1024 + d], w[k], accv); }
  }
  xc[idx] = accv * sigmoidf_(accv);
}

// ---- chunked scan: 32 chunks x 32 steps, thread per (sb,chunk,d), h[16] in registers ----
// processing order u=0..1023, t = s ? 1023-u : u.

#define NCHUNK 32
#define CSTEPS 32

// Pass A: per-chunk h (from h0=0) and sum of dt. hF:[sb][k][512][16], dtsum:[sb][k][512].
__global__ __launch_bounds__(256) void k_scan_a(
  const float* __restrict__ dtv, const float* __restrict__ xc,
  const float* __restrict__ dbl, const float* __restrict__ A_log,
  float* __restrict__ dtsum, float* __restrict__ hF, int layer0)
{
  int d = blockIdx.x*256 + threadIdx.x;
  int k = blockIdx.y;
  int sb = blockIdx.z;
  int s = sb >> 2;
  int layer = layer0 + s;
  float Av[16];
  #pragma unroll
  for (int n=0;n<16;++n) Av[n] = -__expf(A_log[((size_t)layer*512 + d)*16 + n]);
  const float* dt_p = dtv + (size_t)sb*524288 + d;
  const float* xc_p = xc + (size_t)sb*524288 + d;
  const float* bc_p = dbl + (size_t)sb*49152;
  float h[16];
  #pragma unroll
  for (int n=0;n<16;++n) h[n] = 0.f;
  float ssum = 0.f;
  int u0 = k*CSTEPS;
  for (int i=0;i<CSTEPS;++i){
    int u = u0 + i;
    int t = s ? (1023 - u) : u;
    float dtval = dt_p[(size_t)t*512];
    float xv = xc_p[(size_t)t*512];
    const float4* bp = (const float4*)(bc_p + (size_t)t*48 + 16);
    float4 B0 = bp[0], B1 = bp[1], B2 = bp[2], B3 = bp[3];
    float Bv[16] = {B0.x,B0.y,B0.z,B0.w,B1.x,B1.y,B1.z,B1.w,
                    B2.x,B2.y,B2.z,B2.w,B3.x,B3.y,B3.z,B3.w};
    float w = dtval * xv;
    ssum += dtval;
    #pragma unroll
    for (int n=0;n<16;++n)
      h[n] = fmaf(__expf(dtval*Av[n]), h[n], w*Bv[n]);
  }
  size_t base = (size_t)(sb*NCHUNK + k)*512 + d;
  dtsum[base] = ssum;
  float4* hp = (float4*)(hF + base*16);
  #pragma unroll
  for (int q=0;q<4;++q) hp[q] = make_float4(h[4*q],h[4*q+1],h[4*q+2],h[4*q+3]);
}

// Combine: thread per (sb,d,n); serial over chunks; h0 overwrites hF in place.
__global__ __launch_bounds__(256) void k_scan_c(
  const float* __restrict__ dtsum, float* __restrict__ hF,
  const float* __restrict__ A_log, int layer0)
{
  int gid = blockIdx.x*256 + threadIdx.x;  // sb*8192 + d*16 + n
  int sb = gid >> 13;
  int d = (gid >> 4) & 511;
  int n = gid & 15;
  int layer = layer0 + (sb >> 2);
  float Av = -__expf(A_log[((size_t)layer*512 + d)*16 + n]);
  float hrun = 0.f;
  #pragma unroll
  for (int k=0;k<NCHUNK;++k){
    size_t base = (size_t)(sb*NCHUNK + k)*512 + d;
    float a = __expf(Av * dtsum[base]);
    float hf = hF[base*16 + n];
    hF[base*16 + n] = hrun;      // h0 for chunk k
    hrun = fmaf(a, hrun, hf);
  }
}

// Pass B: recompute within chunk from h0, emit gated y in place of dt.
__global__ __launch_bounds__(256) void k_scan_b(
  float* __restrict__ dty, const float* __restrict__ xc, const float* __restrict__ xz,
  const float* __restrict__ dbl, const float* __restrict__ A_log, const float* __restrict__ Dp,
  const float* __restrict__ h0p, int layer0)
{
  int d = blockIdx.x*256 + threadIdx.x;
  int k = blockIdx.y;
  int sb = blockIdx.z;
  int s = sb >> 2;
  int layer = layer0 + s;
  float Av[16];
  #pragma unroll
  for (int n=0;n<16;++n) Av[n] = -__expf(A_log[((size_t)layer*512 + d)*16 + n]);
  float Dv = Dp[(size_t)layer*512 + d];
  float* dt_p = dty + (size_t)sb*524288 + d;
  const float* xc_p = xc + (size_t)sb*524288 + d;
  const float* z_p = xz + (size_t)sb*1048576 + 512 + d;
  const float* bc_p = dbl + (size_t)sb*49152;
  size_t base = (size_t)(sb*NCHUNK + k)*512 + d;
  float h[16];
  const float4* hp = (const float4*)(h0p + base*16);
  #pragma unroll
  for (int q=0;q<4;++q){
    float4 v = hp[q];
    h[4*q]=v.x; h[4*q+1]=v.y; h[4*q+2]=v.z; h[4*q+3]=v.w;
  }
  int u0 = k*CSTEPS;
  for (int i=0;i<CSTEPS;++i){
    int u = u0 + i;
    int t = s ? (1023 - u) : u;
    float dtval = dt_p[(size_t)t*512];
    float xv = xc_p[(size_t)t*512];
    const float4* bp = (const float4*)(bc_p + (size_t)t*48 + 16);
    float4 B0 = bp[0], B1 = bp[1], B2 = bp[2], B3 = bp[3];
    float4 C0 = bp[4], C1 = bp[5], C2 = bp[6], C3 = bp[7];
    float Bv[16] = {B0.x,B0.y,B0.z,B0.w,B1.x,B1.y,B1.z,B1.w,
                    B2.x,B2.y,B2.z,B2.w,B3.x,B3.y,B3.z,B3.w};
    float Cv[16] = {C0.x,C0.y,C0.z,C0.w,C1.x,C1.y,C1.z,C1.w,
                    C2.x,C2.y,C2.z,C2.w,C3.x,C3.y,C3.z,C3.w};
    float w = dtval * xv;
    float y = 0.f;
    #pragma unroll
    for (int n=0;n<16;++n){
      h[n] = fmaf(__expf(dtval*Av[n]), h[n], w*Bv[n]);
      y = fmaf(h[n], Cv[n], y);
    }
    float zv = z_p[(size_t)t*1024];
    dt_p[(size_t)t*512] = (y + Dv*xv) * (zv*sigmoidf_(zv));
  }
}

extern "C" void kernel_launch(void* const* d_in, const int* in_sizes, int n_in,
                              void* d_out, int out_size, void* d_ws, size_t ws_size,
                              hipStream_t stream) {
  const float* x        = (const float*)d_in[0];
  const float* norm_w   = (const float*)d_in[1];
  const float* norm_b   = (const float*)d_in[2];
  const float* in_w     = (const float*)d_in[3];
  const float* conv_w   = (const float*)d_in[4];
  const float* conv_b   = (const float*)d_in[5];
  const float* xproj_w  = (const float*)d_in[6];
  const float* dtproj_w = (const float*)d_in[7];
  const float* dtproj_b = (const float*)d_in[8];
  const float* A_log    = (const float*)d_in[9];
  const float* Dp       = (const float*)d_in[10];
  const float* out_w    = (const float*)d_in[11];
  float* out = (float*)d_out;
  float* ws = (float*)d_ws;

  float* hs   = ws;              // 1048576  (also reused as dtsum scratch mid-iteration)
  float* racc = ws + 1048576;    // 1048576
  float* hn   = ws + 2097152;    // 2097152 (2 streams); dead after in_proj -> reused as hF
  float* xz   = ws + 4194304;    // 8388608
  float* xc   = ws + 12582912;   // 4194304
  float* dbl  = ws + 16777216;   // 393216
  float* dtv  = ws + 17170432;   // 4194304 (dt in, gated y out in-place)
  float* hF    = hn;   // 8 sb x 32 chunk x 512 d x 16 n = 2097152 floats (exact fit)
  float* dtsum = hs;   // 8 sb x 32 chunk x 512 d = 131072 floats; hs free between k_ln and out_proj

  k_transpose_in<<<dim3(32,8,4), dim3(32,8), 0, stream>>>(x, hs);

  for (int it=0; it<2; ++it){
    int layer0 = 2*it;
    k_ln<<<4096, 256, 0, stream>>>(hs, racc, hn, norm_w, norm_b, layer0, it==0 ? 1 : 0);
    // in_proj: xz[s] = hn[s] @ in_w[layer0+s]^T   (M=4096, N=1024, K=256)
    k_gemm<<<dim3(16,64,2), 256, 0, stream>>>(hn, 1048576L, in_w + (size_t)layer0*262144, 262144L,
        xz, 4194304L, nullptr, 0L, 4096, 1024, 256, 256, 256, 1024, 0, 0);
    k_conv<<<16384, 256, 0, stream>>>(xz, xc, conv_w, conv_b, layer0);
    // xproj: dbl[s] = xc[s] @ xproj_w[layer0+s]^T  (M=4096, N=48, K=512)
    k_gemm<<<dim3(1,64,2), 256, 0, stream>>>(xc, 2097152L, xproj_w + (size_t)layer0*24576, 24576L,
        dbl, 196608L, nullptr, 0L, 4096, 48, 512, 512, 512, 48, 0, 0);
    // dtproj: dtv[s] = softplus(dbl[s][:, :16] @ dtproj_w^T + b)  (M=4096, N=512, K=16)
    k_gemm<<<dim3(8,64,2), 256, 0, stream>>>(dbl, 196608L, dtproj_w + (size_t)layer0*8192, 8192L,
        dtv, 2097152L, dtproj_b + (size_t)layer0*512, 512L, 4096, 512, 16, 48, 16, 512, 1, 0);
    // chunked scan
    k_scan_a<<<dim3(2,NCHUNK,8), 256, 0, stream>>>(dtv, xc, dbl, A_log, dtsum, hF, layer0);
    k_scan_c<<<256, 256, 0, stream>>>(dtsum, hF, A_log, layer0);
    k_scan_b<<<dim3(2,NCHUNK,8), 256, 0, stream>>>(dtv, xc, xz, dbl, A_log, Dp, hF, layer0);
    // out_proj: hs = y_f @ out_w[layer0]^T + y_b @ out_w[layer0+1]^T
    k_gemm<<<dim3(4,64,1), 256, 0, stream>>>(dtv, 0L, out_w + (size_t)layer0*131072, 0L,
        hs, 0L, nullptr, 0L, 4096, 256, 512, 512, 512, 256, 0, 0);
    k_gemm<<<dim3(4,64,1), 256, 0, stream>>>(dtv + 2097152, 0L, out_w + (size_t)(layer0+1)*131072, 0L,
        hs, 0L, nullptr, 0L, 4096, 256, 512, 512, 512, 256, 0, 1);
  }
  k_final<<<dim3(32,8,4), dim3(32,8), 0, stream>>>(racc, hs, out);
}

// Round 5
// 443.198 us; speedup vs baseline: 4.4345x; 1.3390x over previous
//
#include <hip/hip_runtime.h>
#include <math.h>

// Dims: B=4 (b*n), L=1024 (h*w), D_MODEL=256, D_INNER=512, D_STATE=16, DT_RANK=16
// Streams: s=0 forward layer (2*it), s=1 backward layer (2*it+1), natural time order.
// GEMMs: bf16 MFMA 16x16x32, operands in fragment-interleaved layout [R/16][K/8][16][8].
// Scan: chunked 2-pass, 32 chunks x 32 steps, thread-per-d with 16 states in registers.

__device__ __forceinline__ float sigmoidf_(float x){ return 1.f/(1.f+__expf(-x)); }
__device__ __forceinline__ short bf16_(float x){
  unsigned u = __float_as_uint(x);
  u += 0x7FFFu + ((u>>16)&1u);
  return (short)(u>>16);
}

using fragAB = __attribute__((ext_vector_type(8))) short;   // 8 bf16
using fragC  = __attribute__((ext_vector_type(4))) float;   // 4 f32

// hs[b,l,c] = x[b,c,l]
__global__ __launch_bounds__(256) void k_transpose_in(const float* __restrict__ x, float* __restrict__ hs){
  __shared__ float tile[32][33];
  int b = blockIdx.z;
  int l0 = blockIdx.x*32, c0 = blockIdx.y*32;
  int tx = threadIdx.x, ty = threadIdx.y;
  #pragma unroll
  for (int j=0;j<32;j+=8)
    tile[ty+j][tx] = x[(size_t)b*262144 + (size_t)(c0+ty+j)*1024 + l0 + tx];
  __syncthreads();
  #pragma unroll
  for (int j=0;j<32;j+=8)
    hs[(size_t)b*262144 + (size_t)(l0+ty+j)*256 + (c0+tx)] = tile[tx][ty+j];
}

// out[b,c,l] = 2*racc[b,l,c] + hs[b,l,c]
__global__ __launch_bounds__(256) void k_final(const float* __restrict__ racc, const float* __restrict__ hs, float* __restrict__ out){
  __shared__ float tile[32][33];
  int b = blockIdx.z;
  int l0 = blockIdx.x*32, c0 = blockIdx.y*32;
  int tx = threadIdx.x, ty = threadIdx.y;
  #pragma unroll
  for (int j=0;j<32;j+=8){
    size_t idx = (size_t)b*262144 + (size_t)(l0+ty+j)*256 + c0+tx;
    tile[ty+j][tx] = 2.f*racc[idx] + hs[idx];
  }
  __syncthreads();
  #pragma unroll
  for (int j=0;j<32;j+=8)
    out[(size_t)b*262144 + (size_t)(c0+ty+j)*1024 + l0+tx] = tile[tx][ty+j];
}

// r = hs (+ 2*racc on iter1); racc = r; hn_frag[s] = bf16frag(LN(r)*nw+nb) for s=0,1
__global__ __launch_bounds__(256) void k_ln(const float* __restrict__ hs, float* __restrict__ racc, short* __restrict__ hn_f,
  const float* __restrict__ nw, const float* __restrict__ nb, int layer0, int first){
  int row = blockIdx.x, c = threadIdx.x;
  size_t idx = (size_t)row*256 + c;
  float r = hs[idx];
  if (!first) r += 2.f*racc[idx];
  racc[idx] = r;
  float s1=r, s2=r*r;
  #pragma unroll
  for (int o=32;o>=1;o>>=1){ s1+=__shfl_xor(s1,o); s2+=__shfl_xor(s2,o); }
  __shared__ float red[8];
  int wid=c>>6, lane=c&63;
  if (lane==0){ red[wid]=s1; red[4+wid]=s2; }
  __syncthreads();
  s1 = red[0]+red[1]+red[2]+red[3];
  s2 = red[4]+red[5]+red[6]+red[7];
  float mu = s1*(1.f/256.f);
  float var = s2*(1.f/256.f) - mu*mu;
  float inv = rsqrtf(var + 1e-5f);
  float nv = (r-mu)*inv;
  size_t fo = (((size_t)(row>>4)*32 + (c>>3))*16 + (row&15))*8 + (c&7);
  hn_f[fo]           = bf16_(nv*nw[layer0*256+c] + nb[layer0*256+c]);
  hn_f[1048576 + fo] = bf16_(nv*nw[(layer0+1)*256+c] + nb[(layer0+1)*256+c]);
}

// Convert weights fp32 -> bf16 fragment layout; which==4 zeroes dt_frag K-pad (ktiles 2,3).
__global__ __launch_bounds__(256) void k_wconv(
  const float* __restrict__ inw, const float* __restrict__ xpw,
  const float* __restrict__ dtw, const float* __restrict__ otw,
  short* __restrict__ f_inw, short* __restrict__ f_xpw,
  short* __restrict__ f_dtw, short* __restrict__ f_otw,
  short* __restrict__ dt_f)
{
  int which = blockIdx.y, layer = blockIdx.z;
  int idx = blockIdx.x*256 + threadIdx.x;
  if (which==4){
    if (layer) return;
    if (idx >= 131072) return;            // 2 streams x 256 mtiles x 2 pad-ktiles x 128
    int st = idx >> 16, rem = idx & 65535;
    int mt = rem >> 8, kt2 = (rem>>7)&1, e = rem&127;
    dt_f[(size_t)st*131072 + ((size_t)(mt*4 + 2 + kt2))*128 + e] = 0;
    return;
  }
  const float* src; short* dst; int R,K,Kp;
  if (which==0){ src=inw; dst=f_inw; R=1024; K=256; Kp=256; }
  else if (which==1){ src=xpw; dst=f_xpw; R=48; K=512; Kp=512; }
  else if (which==2){ src=dtw; dst=f_dtw; R=512; K=16; Kp=32; }
  else { src=otw; dst=f_otw; R=256; K=512; Kp=512; }
  int per = (R>>4)*(Kp>>3)*128;
  if (idx >= per) return;
  int e = idx & 127, tile = idx >> 7;
  int nkt = Kp>>3;
  int kt = tile % nkt, rt = tile / nkt;
  int r = rt*16 + (e>>3), k = kt*8 + (e&7);
  float v = (k<K) ? src[((size_t)layer*R + r)*K + k] : 0.f;
  dst[(size_t)layer*per + idx] = bf16_(v);
}

// bf16 MFMA GEMM: C[M,N] = A @ W^T (+second stream if A2), epilogue by mode.
// A,W in frag layout [R/16][K/8][16][8]. Block 128x64, 4 waves, 64x32 per wave.
// mode 0: plain fp32 store; 1: fp32 store + bf16 dt-frag of cols<16; 2: softplus(v+bias).
__global__ __launch_bounds__(256) void k_mm(
  const short* __restrict__ Af, long sA,
  const short* __restrict__ Wf, long sW,
  const short* __restrict__ A2f, const short* __restrict__ W2f,
  float* __restrict__ Cb, long sC,
  const float* __restrict__ biasb, long sBias,
  int M, int N, int K, int ldc, int mode,
  short* __restrict__ dtf, long sDtf)
{
  int z = blockIdx.z;
  int tid = threadIdx.x;
  int lane = tid & 63, wid = tid >> 6;
  int wm = wid & 1, wn = wid >> 1;
  int K8 = K >> 3;
  int mt_base = blockIdx.y*8 + wm*4;
  int nt_base = blockIdx.x*4 + wn*2;
  int ncap = (N + 15) >> 4;
  const int loff = lane*8;
  fragC acc[4][2] = {};
  const short* Aps[2] = { Af + (size_t)z*sA, A2f };
  const short* Wps[2] = { Wf + (size_t)z*sW, W2f };
  int nseg = A2f ? 2 : 1;
  for (int sgi=0; sgi<nseg; ++sgi){
    const short* A = Aps[sgi];
    const short* W = Wps[sgi];
    for (int kt=0; kt<K8; kt+=4){
      fragAB a[4], b[2];
      #pragma unroll
      for (int i=0;i<4;++i)
        a[i] = *(const fragAB*)(A + ((size_t)(mt_base+i)*K8 + kt)*128 + loff);
      #pragma unroll
      for (int j=0;j<2;++j){
        int nt = nt_base + j; if (nt >= ncap) nt = ncap-1;
        b[j] = *(const fragAB*)(W + ((size_t)nt*K8 + kt)*128 + loff);
      }
      #pragma unroll
      for (int i=0;i<4;++i)
        #pragma unroll
        for (int j=0;j<2;++j)
          acc[i][j] = __builtin_amdgcn_mfma_f32_16x16x32_bf16(a[i], b[j], acc[i][j], 0,0,0);
    }
  }
  float* C = Cb + (size_t)z*sC;
  const float* bias = biasb ? biasb + (size_t)z*sBias : nullptr;
  int r0 = (lane>>4)*4;
  int cc = lane & 15;
  #pragma unroll
  for (int i=0;i<4;++i){
    int row = (mt_base+i)*16 + r0;
    #pragma unroll
    for (int j=0;j<2;++j){
      int col = (nt_base+j)*16 + cc;
      if (col < N){
        #pragma unroll
        for (int r=0;r<4;++r){
          float v = acc[i][j][r];
          if (bias) v += bias[col];
          if (mode==2){ v = (v > 20.f) ? v : log1pf(__expf(v)); }
          C[(size_t)(row+r)*ldc + col] = v;
          if (mode==1 && col < 16){
            int rr = row + r;
            dtf[(size_t)z*sDtf + (((size_t)(rr>>4)*4 + (col>>3))*16 + (rr&15))*8 + (col&7)] = bf16_(v);
          }
        }
      }
    }
  }
}

// causal (s=0) / anticausal (s=1) depthwise conv over t + SiLU; writes fp32 xc + bf16 xc_frag.
__global__ __launch_bounds__(256) void k_conv(const float* __restrict__ xz, float* __restrict__ xc,
  short* __restrict__ xc_f, const float* __restrict__ cw, const float* __restrict__ cb, int layer0){
  int idx = blockIdx.x*256 + threadIdx.x;   // (sb, t, d), d fastest
  int d = idx & 511;
  int t = (idx >> 9) & 1023;
  int sb = idx >> 19;                        // s*4 + b
  int s = sb >> 2, b = sb & 3;
  int layer = layer0 + s;
  const float* w = cw + ((size_t)layer*512 + d)*4;
  float accv = cb[(size_t)layer*512 + d];
  const float* xp = xz + (size_t)sb*1048576;  // row stride 1024, x part at [0:512)
  if (s==0){
    #pragma unroll
    for (int k=0;k<4;++k){ int tt = t + k - 3; if (tt>=0) accv = fmaf(xp[(size_t)tt*1024 + d], w[k], accv); }
  } else {
    #pragma unroll
    for (int k=0;k<4;++k){ int tt = t + 3 - k; if (tt<1024) accv = fmaf(xp[(size_t)tt*1024 + d], w[k], accv); }
  }
  float v = accv * sigmoidf_(accv);
  xc[idx] = v;
  int row = b*1024 + t;
  xc_f[(size_t)s*2097152 + (((size_t)(row>>4)*64 + (d>>3))*16 + (row&15))*8 + (d&7)] = bf16_(v);
}

// ---- chunked scan: 32 chunks x 32 steps, thread per (sb,chunk,d), h[16] in registers ----
#define NCHUNK 32
#define CSTEPS 32

__global__ __launch_bounds__(256) void k_scan_a(
  const float* __restrict__ dtv, const float* __restrict__ xc,
  const float* __restrict__ dbl, const float* __restrict__ A_log,
  float* __restrict__ dtsum, float* __restrict__ hF, int layer0)
{
  int d = blockIdx.x*256 + threadIdx.x;
  int k = blockIdx.y;
  int sb = blockIdx.z;
  int s = sb >> 2;
  int layer = layer0 + s;
  float Av[16];
  #pragma unroll
  for (int n=0;n<16;++n) Av[n] = -__expf(A_log[((size_t)layer*512 + d)*16 + n]);
  const float* dt_p = dtv + (size_t)sb*524288 + d;
  const float* xc_p = xc + (size_t)sb*524288 + d;
  const float* bc_p = dbl + (size_t)sb*49152;
  float h[16];
  #pragma unroll
  for (int n=0;n<16;++n) h[n] = 0.f;
  float ssum = 0.f;
  int u0 = k*CSTEPS;
  for (int i=0;i<CSTEPS;++i){
    int u = u0 + i;
    int t = s ? (1023 - u) : u;
    float dtval = dt_p[(size_t)t*512];
    float xv = xc_p[(size_t)t*512];
    const float4* bp = (const float4*)(bc_p + (size_t)t*48 + 16);
    float4 B0 = bp[0], B1 = bp[1], B2 = bp[2], B3 = bp[3];
    float Bv[16] = {B0.x,B0.y,B0.z,B0.w,B1.x,B1.y,B1.z,B1.w,
                    B2.x,B2.y,B2.z,B2.w,B3.x,B3.y,B3.z,B3.w};
    float w = dtval * xv;
    ssum += dtval;
    #pragma unroll
    for (int n=0;n<16;++n)
      h[n] = fmaf(__expf(dtval*Av[n]), h[n], w*Bv[n]);
  }
  size_t base = (size_t)(sb*NCHUNK + k)*512 + d;
  dtsum[base] = ssum;
  float4* hp = (float4*)(hF + base*16);
  #pragma unroll
  for (int q=0;q<4;++q) hp[q] = make_float4(h[4*q],h[4*q+1],h[4*q+2],h[4*q+3]);
}

__global__ __launch_bounds__(256) void k_scan_c(
  const float* __restrict__ dtsum, float* __restrict__ hF,
  const float* __restrict__ A_log, int layer0)
{
  int gid = blockIdx.x*256 + threadIdx.x;  // sb*8192 + d*16 + n
  int sb = gid >> 13;
  int d = (gid >> 4) & 511;
  int n = gid & 15;
  int layer = layer0 + (sb >> 2);
  float Av = -__expf(A_log[((size_t)layer*512 + d)*16 + n]);
  float hrun = 0.f;
  #pragma unroll
  for (int k=0;k<NCHUNK;++k){
    size_t base = (size_t)(sb*NCHUNK + k)*512 + d;
    float a = __expf(Av * dtsum[base]);
    float hf = hF[base*16 + n];
    hF[base*16 + n] = hrun;      // h0 for chunk k
    hrun = fmaf(a, hrun, hf);
  }
}

// Pass B: recompute within chunk from h0, emit gated y as bf16 fragments (for out_proj).
__global__ __launch_bounds__(256) void k_scan_b(
  const float* __restrict__ dtv, const float* __restrict__ xc, const float* __restrict__ xz,
  const float* __restrict__ dbl, const float* __restrict__ A_log, const float* __restrict__ Dp,
  const float* __restrict__ h0p, short* __restrict__ y_f, int layer0)
{
  int d = blockIdx.x*256 + threadIdx.x;
  int k = blockIdx.y;
  int sb = blockIdx.z;
  int s = sb >> 2, b = sb & 3;
  int layer = layer0 + s;
  float Av[16];
  #pragma unroll
  for (int n=0;n<16;++n) Av[n] = -__expf(A_log[((size_t)layer*512 + d)*16 + n]);
  float Dv = Dp[(size_t)layer*512 + d];
  const float* dt_p = dtv + (size_t)sb*524288 + d;
  const float* xc_p = xc + (size_t)sb*524288 + d;
  const float* z_p = xz + (size_t)sb*1048576 + 512 + d;
  const float* bc_p = dbl + (size_t)sb*49152;
  size_t base = (size_t)(sb*NCHUNK + k)*512 + d;
  float h[16];
  const float4* hp = (const float4*)(h0p + base*16);
  #pragma unroll
  for (int q=0;q<4;++q){
    float4 v = hp[q];
    h[4*q]=v.x; h[4*q+1]=v.y; h[4*q+2]=v.z; h[4*q+3]=v.w;
  }
  short* yo = y_f + (size_t)s*2097152;
  int u0 = k*CSTEPS;
  for (int i=0;i<CSTEPS;++i){
    int u = u0 + i;
    int t = s ? (1023 - u) : u;
    float dtval = dt_p[(size_t)t*512];
    float xv = xc_p[(size_t)t*512];
    const float4* bp = (const float4*)(bc_p + (size_t)t*48 + 16);
    float4 B0 = bp[0], B1 = bp[1], B2 = bp[2], B3 = bp[3];
    float4 C0 = bp[4], C1 = bp[5], C2 = bp[6], C3 = bp[7];
    float Bv[16] = {B0.x,B0.y,B0.z,B0.w,B1.x,B1.y,B1.z,B1.w,
                    B2.x,B2.y,B2.z,B2.w,B3.x,B3.y,B3.z,B3.w};
    float Cv[16] = {C0.x,C0.y,C0.z,C0.w,C1.x,C1.y,C1.z,C1.w,
                    C2.x,C2.y,C2.z,C2.w,C3.x,C3.y,C3.z,C3.w};
    float w = dtval * xv;
    float y = 0.f;
    #pragma unroll
    for (int n=0;n<16;++n){
      h[n] = fmaf(__expf(dtval*Av[n]), h[n], w*Bv[n]);
      y = fmaf(h[n], Cv[n], y);
    }
    float zv = z_p[(size_t)t*1024];
    float yv = (y + Dv*xv) * (zv*sigmoidf_(zv));
    int row = b*1024 + t;
    yo[(((size_t)(row>>4)*64 + (d>>3))*16 + (row&15))*8 + (d&7)] = bf16_(yv);
  }
}

extern "C" void kernel_launch(void* const* d_in, const int* in_sizes, int n_in,
                              void* d_out, int out_size, void* d_ws, size_t ws_size,
                              hipStream_t stream) {
  const float* x        = (const float*)d_in[0];
  const float* norm_w   = (const float*)d_in[1];
  const float* norm_b   = (const float*)d_in[2];
  const float* in_w     = (const float*)d_in[3];
  const float* conv_w   = (const float*)d_in[4];
  const float* conv_b   = (const float*)d_in[5];
  const float* xproj_w  = (const float*)d_in[6];
  const float* dtproj_w = (const float*)d_in[7];
  const float* dtproj_b = (const float*)d_in[8];
  const float* A_log    = (const float*)d_in[9];
  const float* Dp       = (const float*)d_in[10];
  const float* out_w    = (const float*)d_in[11];
  float* out = (float*)d_out;
  float* ws = (float*)d_ws;

  float* hs    = ws;                       // 1048576
  float* racc  = ws + 1048576;             // 1048576
  float* hF    = ws + 2097152;             // 2097152 (scan h0/hF)
  short* hn_f  = (short*)(ws + 2097152);   // aliases hF: 2x1048576 bf16, dead before scan_a
  float* xz    = ws + 4194304;             // 8388608
  float* xc    = ws + 12582912;            // 4194304
  float* dbl   = ws + 16777216;            // 393216
  float* dtv   = ws + 17170432;            // 4194304
  short* xc_f  = (short*)(ws + 21364736);  // 2x2097152 bf16; dead after xproj GEMM
  short* y_f   = xc_f;                     // alias: written by scan_b, read by out_proj, before next conv
  short* dt_f  = (short*)(ws + 23461888);  // 2x131072 bf16 (K padded to 32)
  short* w_inw = (short*)(ws + 23592960);  // 4x262144 bf16
  short* w_xp  = w_inw + 1048576;          // 4x24576
  short* w_dt  = w_xp + 98304;             // 4x16384
  short* w_out = w_dt + 65536;             // 4x131072
  float* dtsum = hs;                       // alias; hs dead between k_ln and out_proj

  k_wconv<<<dim3(1024,5,4), 256, 0, stream>>>(in_w, xproj_w, dtproj_w, out_w,
      w_inw, w_xp, w_dt, w_out, dt_f);
  k_transpose_in<<<dim3(32,8,4), dim3(32,8), 0, stream>>>(x, hs);

  for (int it=0; it<2; ++it){
    int layer0 = 2*it;
    k_ln<<<4096, 256, 0, stream>>>(hs, racc, hn_f, norm_w, norm_b, layer0, it==0 ? 1 : 0);
    // in_proj: xz[s] = hn[s] @ in_w[layer0+s]^T   (M=4096, N=1024, K=256)
    k_mm<<<dim3(16,32,2), 256, 0, stream>>>(hn_f, 1048576L, w_inw + (size_t)layer0*262144, 262144L,
        nullptr, nullptr, xz, 4194304L, nullptr, 0L, 4096, 1024, 256, 1024, 0, nullptr, 0L);
    k_conv<<<16384, 256, 0, stream>>>(xz, xc, xc_f, conv_w, conv_b, layer0);
    // xproj: dbl[s] = xc[s] @ xproj_w[layer0+s]^T  (M=4096, N=48, K=512) + dt frag epilogue
    k_mm<<<dim3(1,32,2), 256, 0, stream>>>(xc_f, 2097152L, w_xp + (size_t)layer0*24576, 24576L,
        nullptr, nullptr, dbl, 196608L, nullptr, 0L, 4096, 48, 512, 48, 1, dt_f, 131072L);
    // dtproj: dtv[s] = softplus(dt[s] @ dtproj_w^T + b)  (M=4096, N=512, K=16 padded to 32)
    k_mm<<<dim3(8,32,2), 256, 0, stream>>>(dt_f, 131072L, w_dt + (size_t)layer0*16384, 16384L,
        nullptr, nullptr, dtv, 2097152L, dtproj_b + (size_t)layer0*512, 512L, 4096, 512, 32, 512, 2, nullptr, 0L);
    // chunked scan
    k_scan_a<<<dim3(2,NCHUNK,8), 256, 0, stream>>>(dtv, xc, dbl, A_log, dtsum, hF, layer0);
    k_scan_c<<<256, 256, 0, stream>>>(dtsum, hF, A_log, layer0);
    k_scan_b<<<dim3(2,NCHUNK,8), 256, 0, stream>>>(dtv, xc, xz, dbl, A_log, Dp, hF, y_f, layer0);
    // out_proj (dual-stream): hs = y_f0 @ out_w[layer0]^T + y_f1 @ out_w[layer0+1]^T
    k_mm<<<dim3(4,32,1), 256, 0, stream>>>(y_f, 0L, w_out + (size_t)layer0*131072, 0L,
        y_f + 2097152, w_out + (size_t)(layer0+1)*131072, hs, 0L, nullptr, 0L,
        4096, 256, 512, 256, 0, nullptr, 0L);
  }
  k_final<<<dim3(32,8,4), dim3(32,8), 0, stream>>>(racc, hs, out);
}